// Round 15
// baseline (108.442 us; speedup 1.0000x reference)
//
#include <hip/hip_runtime.h>
#include <hip/hip_bf16.h>
#include <cstddef>

// ---------- types / helpers ----------
typedef __attribute__((ext_vector_type(8))) short bf16x8;
typedef __attribute__((ext_vector_type(4))) float f32x4;

static __device__ __forceinline__ unsigned short f2bf(float f) {
    unsigned int u = __float_as_uint(f);
    u += 0x7fffu + ((u >> 16) & 1u);
    return (unsigned short)(u >> 16);
}
static __device__ __forceinline__ float bf2f(unsigned short h) {
    return __uint_as_float(((unsigned int)h) << 16);
}

#define B_ 8
#define S_ 1000
#define H_ 768
#define NH_ 12
#define HD_ 64
#define M_ 8000
#define HC_ 2304   // 3*768

// ---------- kernel 1: fused (x = features + pos*scale -> bf16) + (weights -> bf16) ----------
__global__ __launch_bounds__(256)
void prep_all_kernel(const float* __restrict__ feat, const float* __restrict__ pos,
                     const int* __restrict__ level, unsigned short* __restrict__ xb,
                     const float* __restrict__ wq, const float* __restrict__ wk,
                     const float* __restrict__ wv, const float* __restrict__ wo,
                     unsigned short* __restrict__ wdst) {
    const size_t NX = (size_t)M_ * H_ / 4;
    const size_t WSZ = (size_t)H_ * H_;
    size_t gid = (size_t)blockIdx.x * blockDim.x + threadIdx.x;
    if (gid < NX) {
        size_t e = gid * 4;
        float sc = 1.0f + 0.1f * (float)level[0];
        const float4 f = *reinterpret_cast<const float4*>(&feat[e]);
        size_t pe = e % ((size_t)S_ * H_);
        const float4 p = *reinterpret_cast<const float4*>(&pos[pe]);
        ushort4 o;
        o.x = f2bf(f.x + sc * p.x);
        o.y = f2bf(f.y + sc * p.y);
        o.z = f2bf(f.z + sc * p.z);
        o.w = f2bf(f.w + sc * p.w);
        *reinterpret_cast<ushort4*>(&xb[e]) = o;
    } else {
        size_t e = (gid - NX) * 4;
        if (e >= 4 * WSZ) return;
        const float* src; size_t off;
        if (e < WSZ)          { src = wq; off = e; }
        else if (e < 2 * WSZ) { src = wk; off = e - WSZ; }
        else if (e < 3 * WSZ) { src = wv; off = e - 2 * WSZ; }
        else                  { src = wo; off = e - 3 * WSZ; }
        const float4 f = *reinterpret_cast<const float4*>(&src[off]);
        ushort4 o;
        o.x = f2bf(f.x); o.y = f2bf(f.y); o.z = f2bf(f.z); o.w = f2bf(f.w);
        *reinterpret_cast<ushort4*>(&wdst[e]) = o;
    }
}

// ---------- kernel 2: QKV GEMM, 128x128 tile, 8 waves, 64x32/wave, 4-slot deep pipe ----------
// 4 x 16KB half-tile slots (A 8KB | B 8KB each, 32-k halves), stage 3 halves
// ahead. Per phase p: ds_read(slot p&3) -> stage(p+3) -> 8 MFMA -> counted
// drain -> barrier. Drain ledger (R14 bug fixed): outstanding after phase p =
// stages (p+1 .. min(p+3,NP-1)); need stage(p+1) landed ->
// wait = 2*(min(p+3,NP-1)-(p+1)):  p<=NP-4: vmcnt(4); p==NP-3: vmcnt(2);
// p==NP-2: vmcnt(0); p==NP-1: none. Slot reuse safe: stage(p+3) -> slot
// (p-1)&3, whose readers passed phase p-1's trailing barrier.
// Swizzle: phys_slot = log ^ ((row>>1)&3) pre-applied on global source;
// linear gload_lds dest; same XOR on ds_read. Swapped-operand MFMA.
__global__ __launch_bounds__(512, 4)
void gemm_qkv7(const unsigned short* __restrict__ A,
               const unsigned short* __restrict__ Bw,
               const float* __restrict__ b0, const float* __restrict__ b1,
               const float* __restrict__ b2,
               unsigned short* __restrict__ outB) {
    const int K = H_;
    __shared__ char lds[65536];                       // 4 slots x 16KB
    const int tid = threadIdx.x, lane = tid & 63, wid = tid >> 6;
    const int wr = wid >> 2, wc = wid & 3;            // 2 x 4 waves; per-wave 64x32
    const int fr = lane & 15, fq = lane >> 4;

    // bijective XCD swizzle (nwg = 1134, not %8)
    const int nwg = gridDim.x;
    const int q = nwg >> 3, r = nwg & 7;
    const int xcd = blockIdx.x & 7, idx = blockIdx.x >> 3;
    const int swz = (xcd < r) ? (xcd * (q + 1) + idx) : (r * (q + 1) + (xcd - r) * q + idx);
    const int ntn = HC_ / 128;                        // 18
    const int bm = (swz / ntn) * 128;
    const int bn = (swz % ntn) * 128;

    const int srow = lane >> 2;
    const int scol = ((lane & 3) ^ ((lane >> 3) & 3)) * 8;   // pre-swizzled source k-offset

    // stage half p (32 k-cols at p*32): 2 loads/wave into slot p&3
    auto stage = [&](int p) {
        char* base = lds + (p & 3) * 16384;
        const int kk = p * 32;
        int ar = bm + wid * 16 + srow;                // A: 8 chunks of 16 rows; wave w -> chunk w
        ar = ar < M_ ? ar : M_ - 1;                   // clamp: junk rows -> out-rows >= M (skipped)
        __builtin_amdgcn_global_load_lds(
            (const __attribute__((address_space(1))) unsigned int*)(A + (size_t)ar * K + kk + scol),
            (__attribute__((address_space(3))) unsigned int*)(base + wid * 1024), 16, 0, 0);
        const int br = bn + wid * 16 + srow;          // B: HC_ multiple of 128
        __builtin_amdgcn_global_load_lds(
            (const __attribute__((address_space(1))) unsigned int*)(Bw + (size_t)br * K + kk + scol),
            (__attribute__((address_space(3))) unsigned int*)(base + 8192 + wid * 1024), 16, 0, 0);
    };

    f32x4 acc[4][2] = {};
    const int rsl = fq ^ ((fr >> 1) & 3);
    const int NP = K / 32;                            // 24 phases

    stage(0); stage(1); stage(2);                     // 6 loads/wave in flight
    asm volatile("s_waitcnt vmcnt(4)" ::: "memory");  // slot0 landed
    __builtin_amdgcn_s_barrier();

    for (int p = 0; p < NP; ++p) {
        char* half = lds + (p & 3) * 16384;
        bf16x8 af[4], bfv[2];
#pragma unroll
        for (int m = 0; m < 4; ++m) {
            const int row = wr * 64 + m * 16 + fr;
            af[m] = *reinterpret_cast<const bf16x8*>(half + row * 64 + rsl * 16);
        }
#pragma unroll
        for (int n = 0; n < 2; ++n) {
            const int row = wc * 32 + n * 16 + fr;
            bfv[n] = *reinterpret_cast<const bf16x8*>(half + 8192 + row * 64 + rsl * 16);
        }
        if (p + 3 < NP) stage(p + 3);                 // into slot (p-1)&3: safe (readers barrier'd)
        __builtin_amdgcn_s_setprio(1);
#pragma unroll
        for (int m = 0; m < 4; ++m)
#pragma unroll
            for (int n = 0; n < 2; ++n)
                acc[m][n] = __builtin_amdgcn_mfma_f32_16x16x32_bf16(bfv[n], af[m], acc[m][n], 0, 0, 0);
        __builtin_amdgcn_s_setprio(0);
        // drain: need stage(p+1) landed; outstanding = stages (p+1..min(p+3,NP-1))
        if (p + 3 < NP)       { asm volatile("s_waitcnt vmcnt(4)" ::: "memory"); }
        else if (p == NP - 3) { asm volatile("s_waitcnt vmcnt(2)" ::: "memory"); }
        else if (p == NP - 2) { asm volatile("s_waitcnt vmcnt(0)" ::: "memory"); }
        // p == NP-1: epilogue only, no wait needed
        if (p + 1 < NP) __builtin_amdgcn_s_barrier();
    }

    // epilogue: row = bm + wr*64 + m*16 + fr (thread-fixed), col = bn + wc*32 + n*16 + fq*4 + j
    const int colg = (bn < 768) ? bn : (bn < 1536) ? bn - 768 : bn - 1536;
    const float* bsel = (bn < 768) ? b0 : (bn < 1536) ? b1 : b2;
#pragma unroll
    for (int m = 0; m < 4; ++m) {
        const int row = bm + wr * 64 + m * 16 + fr;
        if (row >= M_) continue;
#pragma unroll
        for (int n = 0; n < 2; ++n) {
            const int cb = wc * 32 + n * 16 + fq * 4;
            const float4 bv = *reinterpret_cast<const float4*>(&bsel[colg + cb]);
            ushort4 o;
            o.x = f2bf(acc[m][n][0] + bv.x);
            o.y = f2bf(acc[m][n][1] + bv.y);
            o.z = f2bf(acc[m][n][2] + bv.z);
            o.w = f2bf(acc[m][n][3] + bv.w);
            *reinterpret_cast<ushort4*>(&outB[(size_t)row * HC_ + bn + cb]) = o;
        }
    }
}

// ---------- kernel 4: out-proj GEMM (R13 proven), 128x64 tile, BK=64-pair ----------
__global__ __launch_bounds__(256, 4)
void gemm_out4(const unsigned short* __restrict__ A,   // [8000][768] ctx
               const unsigned short* __restrict__ Bw,  // [768][768] Wo
               const float* __restrict__ b0,
               const float* __restrict__ resid,
               float* __restrict__ outF) {
    const int K = H_;
    __shared__ char lds[49152];                        // 2 buffers x 2 sub-tiles x 12KB
    const int tid = threadIdx.x, lane = tid & 63, wid = tid >> 6;
    const int wr = wid >> 1, wc = wid & 1;             // 2 x 2 waves; per-wave 64x32
    const int fr = lane & 15, fq = lane >> 4;

    const int nwg = gridDim.x;                         // 756
    const int q = nwg >> 3, r = nwg & 7;
    const int xcd = blockIdx.x & 7, idx = blockIdx.x >> 3;
    const int swz = (xcd < r) ? (xcd * (q + 1) + idx) : (r * (q + 1) + (xcd - r) * q + idx);
    const int ntn = H_ / 64;
    const int bm = (swz / ntn) * 128;
    const int bn = (swz % ntn) * 64;

    const int srow = lane >> 2;
    const int scol = ((lane & 3) ^ ((lane >> 3) & 3)) * 8;

    auto stage = [&](int buf, int k0) {
        char* base = lds + buf * 24576;
#pragma unroll
        for (int s = 0; s < 2; ++s) {
            char* half = base + s * 12288;
            const int kk = k0 + s * 32;
#pragma unroll
            for (int t = 0; t < 2; ++t) {
                const int c = wid * 2 + t;             // A chunks 0..7
                int ar = bm + c * 16 + srow;
                ar = ar < M_ ? ar : M_ - 1;
                __builtin_amdgcn_global_load_lds(
                    (const __attribute__((address_space(1))) unsigned int*)(A + (size_t)ar * K + kk + scol),
                    (__attribute__((address_space(3))) unsigned int*)(half + c * 1024), 16, 0, 0);
            }
            const int br = bn + wid * 16 + srow;       // B chunks 0..3 (H_ mult of 64)
            __builtin_amdgcn_global_load_lds(
                (const __attribute__((address_space(1))) unsigned int*)(Bw + (size_t)br * K + kk + scol),
                (__attribute__((address_space(3))) unsigned int*)(half + 8192 + wid * 1024), 16, 0, 0);
        }
    };

    f32x4 acc[4][2] = {};
    const int rsl = fq ^ ((fr >> 1) & 3);
    const int NT = K / 64;                             // 12

    stage(0, 0);                                       // 6 loads/wave
    for (int t = 0; t < NT; ++t) {
        const int cur = t & 1;
        if (t + 1 < NT) {
            stage(cur ^ 1, (t + 1) * 64);              // +6 -> 12 outstanding
            asm volatile("s_waitcnt vmcnt(6)" ::: "memory");   // oldest 6 (tile t) landed
        } else {
            asm volatile("s_waitcnt vmcnt(0)" ::: "memory");
        }
        __builtin_amdgcn_s_barrier();

        char* base = lds + cur * 24576;
#pragma unroll
        for (int s = 0; s < 2; ++s) {
            char* half = base + s * 12288;
            bf16x8 af[4], bfv[2];
#pragma unroll
            for (int m = 0; m < 4; ++m) {
                const int row = wr * 64 + m * 16 + fr;
                af[m] = *reinterpret_cast<const bf16x8*>(half + row * 64 + rsl * 16);
            }
#pragma unroll
            for (int n = 0; n < 2; ++n) {
                const int row = wc * 32 + n * 16 + fr;
                bfv[n] = *reinterpret_cast<const bf16x8*>(half + 8192 + row * 64 + rsl * 16);
            }
            __builtin_amdgcn_s_setprio(1);
#pragma unroll
            for (int m = 0; m < 4; ++m)
#pragma unroll
                for (int n = 0; n < 2; ++n)
                    acc[m][n] = __builtin_amdgcn_mfma_f32_16x16x32_bf16(bfv[n], af[m], acc[m][n], 0, 0, 0);
            __builtin_amdgcn_s_setprio(0);
        }
        __builtin_amdgcn_s_barrier();
    }

#pragma unroll
    for (int m = 0; m < 4; ++m) {
        const int row = bm + wr * 64 + m * 16 + fr;
        if (row >= M_) continue;
#pragma unroll
        for (int n = 0; n < 2; ++n) {
            const int col = bn + wc * 32 + n * 16 + fq * 4;
            const float4 bv = *reinterpret_cast<const float4*>(&b0[col]);
            const float4 rv = *reinterpret_cast<const float4*>(&resid[(size_t)row * H_ + col]);
            float4 ov;
            ov.x = acc[m][n][0] + bv.x + rv.x;
            ov.y = acc[m][n][1] + bv.y + rv.y;
            ov.z = acc[m][n][2] + bv.z + rv.z;
            ov.w = acc[m][n][3] + bv.w + rv.w;
            *reinterpret_cast<float4*>(&outF[(size_t)row * H_ + col]) = ov;
        }
    }
}

// ---------- kernel 3: banded attention, 16 queries/wave, 4 lanes x 16 dims ----------
__global__ __launch_bounds__(256)
void attn_kernel(const unsigned short* __restrict__ QKV,
                 unsigned short* __restrict__ ctx,
                 const int* __restrict__ level_p) {
    const int lane = threadIdx.x & 63;
    const int wv = threadIdx.x >> 6;
    const int qiw = lane >> 2;
    const int d0 = (lane & 3) * 16;

    const int qt = blockIdx.x & 15;
    const int h  = (blockIdx.x >> 4) % NH_;
    const int b  = blockIdx.x / (16 * NH_);
    const int i  = qt * 64 + wv * 16 + qiw;
    const bool valid = i < S_;
    const int iq = valid ? i : S_ - 1;

    const int lev = level_p[0];
    const int w = (lev == 0) ? 2 : (lev == 1) ? 5 : S_;

    const size_t qoff = (size_t)(b * S_ + iq) * HC_ + h * HD_ + d0;
    bf16x8 qa = *reinterpret_cast<const bf16x8*>(&QKV[qoff]);
    bf16x8 qb = *reinterpret_cast<const bf16x8*>(&QKV[qoff + 8]);
    float qf[16];
#pragma unroll
    for (int t = 0; t < 8; ++t) {
        qf[t]     = bf2f((unsigned short)qa[t]);
        qf[t + 8] = bf2f((unsigned short)qb[t]);
    }

    const int j0 = max(0, i - w), j1 = min(S_ - 1, i + w);
    float mx = -1e30f, l = 0.f;
    float acc[16];
#pragma unroll
    for (int t = 0; t < 16; ++t) acc[t] = 0.f;

    for (int jc = j0; jc <= j1; jc += 5) {
        float s[5];
        int jj[5];
#pragma unroll
        for (int t = 0; t < 5; ++t) {
            const int j = jc + t;
            jj[t] = j <= j1 ? j : j1;
            const size_t koff = (size_t)(b * S_ + jj[t]) * HC_ + 768 + h * HD_ + d0;
            bf16x8 ka = *reinterpret_cast<const bf16x8*>(&QKV[koff]);
            bf16x8 kb = *reinterpret_cast<const bf16x8*>(&QKV[koff + 8]);
            float p = 0.f;
#pragma unroll
            for (int d = 0; d < 8; ++d) {
                p = fmaf(qf[d], bf2f((unsigned short)ka[d]), p);
                p = fmaf(qf[d + 8], bf2f((unsigned short)kb[d]), p);
            }
            s[t] = p;
        }
#pragma unroll
        for (int t = 0; t < 5; ++t) s[t] += __shfl_xor(s[t], 1);
#pragma unroll
        for (int t = 0; t < 5; ++t) s[t] += __shfl_xor(s[t], 2);
#pragma unroll
        for (int t = 0; t < 5; ++t)
            s[t] = (jc + t <= j1) ? s[t] * 0.125f : -1e30f;

        float cm = fmaxf(fmaxf(fmaxf(s[0], s[1]), fmaxf(s[2], s[3])), s[4]);
        float nm = fmaxf(mx, cm);
        float corr = __expf(mx - nm);
        l *= corr;
#pragma unroll
        for (int t = 0; t < 16; ++t) acc[t] *= corr;
#pragma unroll
        for (int t = 0; t < 5; ++t) {
            const float e = __expf(s[t] - nm);
            l += e;
            const size_t voff = (size_t)(b * S_ + jj[t]) * HC_ + 1536 + h * HD_ + d0;
            bf16x8 va = *reinterpret_cast<const bf16x8*>(&QKV[voff]);
            bf16x8 vb = *reinterpret_cast<const bf16x8*>(&QKV[voff + 8]);
#pragma unroll
            for (int d = 0; d < 8; ++d) {
                acc[d]     = fmaf(e, bf2f((unsigned short)va[d]), acc[d]);
                acc[d + 8] = fmaf(e, bf2f((unsigned short)vb[d]), acc[d + 8]);
            }
        }
        mx = nm;
    }

    if (valid) {
        const float inv = 1.f / l;
        bf16x8 o0, o1;
#pragma unroll
        for (int t = 0; t < 8; ++t) {
            o0[t] = (short)f2bf(acc[t] * inv);
            o1[t] = (short)f2bf(acc[t + 8] * inv);
        }
        unsigned short* dst = &ctx[(size_t)(b * S_ + i) * H_ + h * HD_ + d0];
        *reinterpret_cast<bf16x8*>(dst) = o0;
        *reinterpret_cast<bf16x8*>(dst + 8) = o1;
    }
}

// ---------- kernel 5: in-place LayerNorm over rows of d_out ----------
__global__ __launch_bounds__(256)
void ln_kernel(float* __restrict__ y, const float* __restrict__ g, const float* __restrict__ bta) {
    int row = blockIdx.x;
    int tid = threadIdx.x;
    float* p = y + (size_t)row * H_;
    float v[3];
    float s = 0.f, s2 = 0.f;
#pragma unroll
    for (int t = 0; t < 3; ++t) {
        v[t] = p[tid + t * 256];
        s += v[t];
        s2 += v[t] * v[t];
    }
#pragma unroll
    for (int o = 32; o; o >>= 1) {
        s  += __shfl_xor(s, o);
        s2 += __shfl_xor(s2, o);
    }
    __shared__ float ss[4], ss2[4];
    if ((tid & 63) == 0) { ss[tid >> 6] = s; ss2[tid >> 6] = s2; }
    __syncthreads();
    s  = ss[0] + ss[1] + ss[2] + ss[3];
    s2 = ss2[0] + ss2[1] + ss2[2] + ss2[3];
    float mu = s * (1.f / H_);
    float var = s2 * (1.f / H_) - mu * mu;
    float rs = rsqrtf(var + 1e-5f);
#pragma unroll
    for (int t = 0; t < 3; ++t) {
        int c = tid + t * 256;
        p[c] = (v[t] - mu) * rs * g[c] + bta[c];
    }
}

// ---------- launch ----------
extern "C" void kernel_launch(void* const* d_in, const int* in_sizes, int n_in,
                              void* d_out, int out_size, void* d_ws, size_t ws_size,
                              hipStream_t stream) {
    const float* feat  = (const float*)d_in[0];
    const float* pos   = (const float*)d_in[1];
    const float* Wq    = (const float*)d_in[2];
    const float* bq    = (const float*)d_in[3];
    const float* Wk    = (const float*)d_in[4];
    const float* bk    = (const float*)d_in[5];
    const float* Wv    = (const float*)d_in[6];
    const float* bv    = (const float*)d_in[7];
    const float* Wo    = (const float*)d_in[8];
    const float* bo    = (const float*)d_in[9];
    const float* ln_g  = (const float*)d_in[10];
    const float* ln_b  = (const float*)d_in[11];
    const int*   level = (const int*)d_in[12];
    float* out = (float*)d_out;

    char* ws = (char*)d_ws;
    unsigned short* xb   = (unsigned short*)ws;                      // [8000][768]
    unsigned short* Wcat = xb + (size_t)M_ * H_;                     // [3072][768] = Wq|Wk|Wv|Wo
    unsigned short* QKVb = Wcat + (size_t)4 * H_ * H_;               // [8000][2304]
    unsigned short* ctxb = QKVb + (size_t)M_ * HC_;                  // [8000][768]

    // 1) fused x-prep + weight cast
    const int nprep = (int)(((size_t)M_ * H_ / 4 + (size_t)4 * H_ * H_ / 4 + 255) / 256);
    prep_all_kernel<<<nprep, 256, 0, stream>>>(feat, pos, level, xb, Wq, Wk, Wv, Wo, Wcat);
    // 2) QKV = x @ [Wq|Wk|Wv]^T + bias   (grid 63x18 = 1134, 512 thr)
    gemm_qkv7<<<63 * 18, 512, 0, stream>>>(xb, Wcat, bq, bk, bv, QKVb);
    // 3) banded attention -> ctx (bf16)
    attn_kernel<<<B_ * NH_ * 16, 256, 0, stream>>>(QKVb, ctxb, level);
    // 4) y = ctx @ Wo^T + bo + features  (grid 63x12 = 756, 256 thr)
    gemm_out4<<<63 * 12, 256, 0, stream>>>(ctxb, Wcat + (size_t)3 * H_ * H_, bo, feat, out);
    // 5) LayerNorm in place on d_out
    ln_kernel<<<M_, 256, 0, stream>>>(out, ln_g, ln_b);
}

// Round 16
// 106.960 us; speedup vs baseline: 1.0139x; 1.0139x over previous
//
#include <hip/hip_runtime.h>
#include <hip/hip_bf16.h>
#include <cstddef>

// ---------- types / helpers ----------
typedef __attribute__((ext_vector_type(8))) short bf16x8;
typedef __attribute__((ext_vector_type(4))) float f32x4;

static __device__ __forceinline__ unsigned short f2bf(float f) {
    unsigned int u = __float_as_uint(f);
    u += 0x7fffu + ((u >> 16) & 1u);
    return (unsigned short)(u >> 16);
}
static __device__ __forceinline__ float bf2f(unsigned short h) {
    return __uint_as_float(((unsigned int)h) << 16);
}

#define B_ 8
#define S_ 1000
#define H_ 768
#define NH_ 12
#define HD_ 64
#define M_ 8000
#define HC_ 2304   // 3*768

// ---------- kernel 1: fused (x = features + pos*scale -> bf16) + (weights -> bf16) ----------
__global__ __launch_bounds__(256)
void prep_all_kernel(const float* __restrict__ feat, const float* __restrict__ pos,
                     const int* __restrict__ level, unsigned short* __restrict__ xb,
                     const float* __restrict__ wq, const float* __restrict__ wk,
                     const float* __restrict__ wv, const float* __restrict__ wo,
                     unsigned short* __restrict__ wdst) {
    const size_t NX = (size_t)M_ * H_ / 4;
    const size_t WSZ = (size_t)H_ * H_;
    size_t gid = (size_t)blockIdx.x * blockDim.x + threadIdx.x;
    if (gid < NX) {
        size_t e = gid * 4;
        float sc = 1.0f + 0.1f * (float)level[0];
        const float4 f = *reinterpret_cast<const float4*>(&feat[e]);
        size_t pe = e % ((size_t)S_ * H_);
        const float4 p = *reinterpret_cast<const float4*>(&pos[pe]);
        ushort4 o;
        o.x = f2bf(f.x + sc * p.x);
        o.y = f2bf(f.y + sc * p.y);
        o.z = f2bf(f.z + sc * p.z);
        o.w = f2bf(f.w + sc * p.w);
        *reinterpret_cast<ushort4*>(&xb[e]) = o;
    } else {
        size_t e = (gid - NX) * 4;
        if (e >= 4 * WSZ) return;
        const float* src; size_t off;
        if (e < WSZ)          { src = wq; off = e; }
        else if (e < 2 * WSZ) { src = wk; off = e - WSZ; }
        else if (e < 3 * WSZ) { src = wv; off = e - 2 * WSZ; }
        else                  { src = wo; off = e - 3 * WSZ; }
        const float4 f = *reinterpret_cast<const float4*>(&src[off]);
        ushort4 o;
        o.x = f2bf(f.x); o.y = f2bf(f.y); o.z = f2bf(f.z); o.w = f2bf(f.w);
        *reinterpret_cast<ushort4*>(&wdst[e]) = o;
    }
}

// ---------- kernel 2: QKV GEMM (R13 best, 48.8us), 128x128 tile, 8 waves, 64x32/wave ----------
// BK=64 per barrier-pair: each 32KB buffer = two 16KB sub-tiles (swizzled
// [128rows][32k] 64B-row layout). Double-buffered, counted vmcnt(4), 12
// barrier-pairs. bounds(512,4). Swizzle: phys_slot = log ^ ((row>>1)&3)
// pre-applied on global source; linear gload_lds dest; same XOR on ds_read.
// Swapped-operand MFMA -> thread holds 4 consecutive cols -> ushort4 stores.
__global__ __launch_bounds__(512, 4)
void gemm_qkv5(const unsigned short* __restrict__ A,
               const unsigned short* __restrict__ Bw,
               const float* __restrict__ b0, const float* __restrict__ b1,
               const float* __restrict__ b2,
               unsigned short* __restrict__ outB) {
    const int K = H_;
    __shared__ char lds[65536];                       // 2 buffers x 2 sub-tiles x 16KB
    const int tid = threadIdx.x, lane = tid & 63, wid = tid >> 6;
    const int wr = wid >> 2, wc = wid & 3;            // 2 x 4 waves; per-wave 64x32
    const int fr = lane & 15, fq = lane >> 4;

    // bijective XCD swizzle (nwg = 1134, not %8)
    const int nwg = gridDim.x;
    const int q = nwg >> 3, r = nwg & 7;
    const int xcd = blockIdx.x & 7, idx = blockIdx.x >> 3;
    const int swz = (xcd < r) ? (xcd * (q + 1) + idx) : (r * (q + 1) + (xcd - r) * q + idx);
    const int ntn = HC_ / 128;                        // 18
    const int bm = (swz / ntn) * 128;
    const int bn = (swz % ntn) * 128;

    const int srow = lane >> 2;
    const int scol = ((lane & 3) ^ ((lane >> 3) & 3)) * 8;   // pre-swizzled source k-offset

    // stage one BK=64 tile = 2 sub-tiles; 4 loads/wave
    auto stage = [&](int buf, int k0) {
        char* base = lds + buf * 32768;
#pragma unroll
        for (int s = 0; s < 2; ++s) {
            char* half = base + s * 16384;
            const int kk = k0 + s * 32;
            int ar = bm + wid * 16 + srow;            // 8 chunks of 16 rows; wave w -> chunk w
            ar = ar < M_ ? ar : M_ - 1;               // clamp: junk rows -> out-rows >= M (skipped)
            __builtin_amdgcn_global_load_lds(
                (const __attribute__((address_space(1))) unsigned int*)(A + (size_t)ar * K + kk + scol),
                (__attribute__((address_space(3))) unsigned int*)(half + wid * 1024), 16, 0, 0);
            const int br = bn + wid * 16 + srow;      // HC_ multiple of 128
            __builtin_amdgcn_global_load_lds(
                (const __attribute__((address_space(1))) unsigned int*)(Bw + (size_t)br * K + kk + scol),
                (__attribute__((address_space(3))) unsigned int*)(half + 8192 + wid * 1024), 16, 0, 0);
        }
    };

    f32x4 acc[4][2] = {};
    const int rsl = fq ^ ((fr >> 1) & 3);
    const int NT = K / 64;                            // 12

    stage(0, 0);                                      // 4 loads/wave in flight
    for (int t = 0; t < NT; ++t) {
        const int cur = t & 1;
        if (t + 1 < NT) {
            stage(cur ^ 1, (t + 1) * 64);             // +4 -> 8 outstanding
            asm volatile("s_waitcnt vmcnt(4)" ::: "memory");   // oldest 4 (tile t) landed
        } else {
            asm volatile("s_waitcnt vmcnt(0)" ::: "memory");
        }
        __builtin_amdgcn_s_barrier();                 // tile t visible to all waves

        char* base = lds + cur * 32768;
#pragma unroll
        for (int s = 0; s < 2; ++s) {                 // two 32-k sub-steps per barrier-pair
            char* half = base + s * 16384;
            bf16x8 af[4], bfv[2];
#pragma unroll
            for (int m = 0; m < 4; ++m) {
                const int row = wr * 64 + m * 16 + fr;
                af[m] = *reinterpret_cast<const bf16x8*>(half + row * 64 + rsl * 16);
            }
#pragma unroll
            for (int n = 0; n < 2; ++n) {
                const int row = wc * 32 + n * 16 + fr;
                bfv[n] = *reinterpret_cast<const bf16x8*>(half + 8192 + row * 64 + rsl * 16);
            }
            __builtin_amdgcn_s_setprio(1);
#pragma unroll
            for (int m = 0; m < 4; ++m)
#pragma unroll
                for (int n = 0; n < 2; ++n)
                    acc[m][n] = __builtin_amdgcn_mfma_f32_16x16x32_bf16(bfv[n], af[m], acc[m][n], 0, 0, 0);
            __builtin_amdgcn_s_setprio(0);
        }
        __builtin_amdgcn_s_barrier();                 // reads done before buffer reuse
    }

    // epilogue: row = bm + wr*64 + m*16 + fr (thread-fixed), col = bn + wc*32 + n*16 + fq*4 + j
    const int colg = (bn < 768) ? bn : (bn < 1536) ? bn - 768 : bn - 1536;
    const float* bsel = (bn < 768) ? b0 : (bn < 1536) ? b1 : b2;
#pragma unroll
    for (int m = 0; m < 4; ++m) {
        const int row = bm + wr * 64 + m * 16 + fr;
        if (row >= M_) continue;
#pragma unroll
        for (int n = 0; n < 2; ++n) {
            const int cb = wc * 32 + n * 16 + fq * 4;
            const float4 bv = *reinterpret_cast<const float4*>(&bsel[colg + cb]);
            ushort4 o;
            o.x = f2bf(acc[m][n][0] + bv.x);
            o.y = f2bf(acc[m][n][1] + bv.y);
            o.z = f2bf(acc[m][n][2] + bv.z);
            o.w = f2bf(acc[m][n][3] + bv.w);
            *reinterpret_cast<ushort4*>(&outB[(size_t)row * HC_ + bn + cb]) = o;
        }
    }
}

// ---------- kernel 4: out-proj GEMM (R13 proven), 128x64 tile, BK=64-pair ----------
__global__ __launch_bounds__(256, 4)
void gemm_out4(const unsigned short* __restrict__ A,   // [8000][768] ctx
               const unsigned short* __restrict__ Bw,  // [768][768] Wo
               const float* __restrict__ b0,
               const float* __restrict__ resid,
               float* __restrict__ outF) {
    const int K = H_;
    __shared__ char lds[49152];                        // 2 buffers x 2 sub-tiles x 12KB
    const int tid = threadIdx.x, lane = tid & 63, wid = tid >> 6;
    const int wr = wid >> 1, wc = wid & 1;             // 2 x 2 waves; per-wave 64x32
    const int fr = lane & 15, fq = lane >> 4;

    const int nwg = gridDim.x;                         // 756
    const int q = nwg >> 3, r = nwg & 7;
    const int xcd = blockIdx.x & 7, idx = blockIdx.x >> 3;
    const int swz = (xcd < r) ? (xcd * (q + 1) + idx) : (r * (q + 1) + (xcd - r) * q + idx);
    const int ntn = H_ / 64;
    const int bm = (swz / ntn) * 128;
    const int bn = (swz % ntn) * 64;

    const int srow = lane >> 2;
    const int scol = ((lane & 3) ^ ((lane >> 3) & 3)) * 8;

    auto stage = [&](int buf, int k0) {
        char* base = lds + buf * 24576;
#pragma unroll
        for (int s = 0; s < 2; ++s) {
            char* half = base + s * 12288;
            const int kk = k0 + s * 32;
#pragma unroll
            for (int t = 0; t < 2; ++t) {
                const int c = wid * 2 + t;             // A chunks 0..7
                int ar = bm + c * 16 + srow;
                ar = ar < M_ ? ar : M_ - 1;
                __builtin_amdgcn_global_load_lds(
                    (const __attribute__((address_space(1))) unsigned int*)(A + (size_t)ar * K + kk + scol),
                    (__attribute__((address_space(3))) unsigned int*)(half + c * 1024), 16, 0, 0);
            }
            const int br = bn + wid * 16 + srow;       // B chunks 0..3 (H_ mult of 64)
            __builtin_amdgcn_global_load_lds(
                (const __attribute__((address_space(1))) unsigned int*)(Bw + (size_t)br * K + kk + scol),
                (__attribute__((address_space(3))) unsigned int*)(half + 8192 + wid * 1024), 16, 0, 0);
        }
    };

    f32x4 acc[4][2] = {};
    const int rsl = fq ^ ((fr >> 1) & 3);
    const int NT = K / 64;                             // 12

    stage(0, 0);                                       // 6 loads/wave
    for (int t = 0; t < NT; ++t) {
        const int cur = t & 1;
        if (t + 1 < NT) {
            stage(cur ^ 1, (t + 1) * 64);              // +6 -> 12 outstanding
            asm volatile("s_waitcnt vmcnt(6)" ::: "memory");   // oldest 6 (tile t) landed
        } else {
            asm volatile("s_waitcnt vmcnt(0)" ::: "memory");
        }
        __builtin_amdgcn_s_barrier();

        char* base = lds + cur * 24576;
#pragma unroll
        for (int s = 0; s < 2; ++s) {
            char* half = base + s * 12288;
            bf16x8 af[4], bfv[2];
#pragma unroll
            for (int m = 0; m < 4; ++m) {
                const int row = wr * 64 + m * 16 + fr;
                af[m] = *reinterpret_cast<const bf16x8*>(half + row * 64 + rsl * 16);
            }
#pragma unroll
            for (int n = 0; n < 2; ++n) {
                const int row = wc * 32 + n * 16 + fr;
                bfv[n] = *reinterpret_cast<const bf16x8*>(half + 8192 + row * 64 + rsl * 16);
            }
            __builtin_amdgcn_s_setprio(1);
#pragma unroll
            for (int m = 0; m < 4; ++m)
#pragma unroll
                for (int n = 0; n < 2; ++n)
                    acc[m][n] = __builtin_amdgcn_mfma_f32_16x16x32_bf16(bfv[n], af[m], acc[m][n], 0, 0, 0);
            __builtin_amdgcn_s_setprio(0);
        }
        __builtin_amdgcn_s_barrier();
    }

#pragma unroll
    for (int m = 0; m < 4; ++m) {
        const int row = bm + wr * 64 + m * 16 + fr;
        if (row >= M_) continue;
#pragma unroll
        for (int n = 0; n < 2; ++n) {
            const int col = bn + wc * 32 + n * 16 + fq * 4;
            const float4 bv = *reinterpret_cast<const float4*>(&b0[col]);
            const float4 rv = *reinterpret_cast<const float4*>(&resid[(size_t)row * H_ + col]);
            float4 ov;
            ov.x = acc[m][n][0] + bv.x + rv.x;
            ov.y = acc[m][n][1] + bv.y + rv.y;
            ov.z = acc[m][n][2] + bv.z + rv.z;
            ov.w = acc[m][n][3] + bv.w + rv.w;
            *reinterpret_cast<float4*>(&outF[(size_t)row * H_ + col]) = ov;
        }
    }
}

// ---------- kernel 3: banded attention, 16 queries/wave, 4 lanes x 16 dims ----------
__global__ __launch_bounds__(256)
void attn_kernel(const unsigned short* __restrict__ QKV,
                 unsigned short* __restrict__ ctx,
                 const int* __restrict__ level_p) {
    const int lane = threadIdx.x & 63;
    const int wv = threadIdx.x >> 6;
    const int qiw = lane >> 2;
    const int d0 = (lane & 3) * 16;

    const int qt = blockIdx.x & 15;
    const int h  = (blockIdx.x >> 4) % NH_;
    const int b  = blockIdx.x / (16 * NH_);
    const int i  = qt * 64 + wv * 16 + qiw;
    const bool valid = i < S_;
    const int iq = valid ? i : S_ - 1;

    const int lev = level_p[0];
    const int w = (lev == 0) ? 2 : (lev == 1) ? 5 : S_;

    const size_t qoff = (size_t)(b * S_ + iq) * HC_ + h * HD_ + d0;
    bf16x8 qa = *reinterpret_cast<const bf16x8*>(&QKV[qoff]);
    bf16x8 qb = *reinterpret_cast<const bf16x8*>(&QKV[qoff + 8]);
    float qf[16];
#pragma unroll
    for (int t = 0; t < 8; ++t) {
        qf[t]     = bf2f((unsigned short)qa[t]);
        qf[t + 8] = bf2f((unsigned short)qb[t]);
    }

    const int j0 = max(0, i - w), j1 = min(S_ - 1, i + w);
    float mx = -1e30f, l = 0.f;
    float acc[16];
#pragma unroll
    for (int t = 0; t < 16; ++t) acc[t] = 0.f;

    for (int jc = j0; jc <= j1; jc += 5) {
        float s[5];
        int jj[5];
#pragma unroll
        for (int t = 0; t < 5; ++t) {
            const int j = jc + t;
            jj[t] = j <= j1 ? j : j1;
            const size_t koff = (size_t)(b * S_ + jj[t]) * HC_ + 768 + h * HD_ + d0;
            bf16x8 ka = *reinterpret_cast<const bf16x8*>(&QKV[koff]);
            bf16x8 kb = *reinterpret_cast<const bf16x8*>(&QKV[koff + 8]);
            float p = 0.f;
#pragma unroll
            for (int d = 0; d < 8; ++d) {
                p = fmaf(qf[d], bf2f((unsigned short)ka[d]), p);
                p = fmaf(qf[d + 8], bf2f((unsigned short)kb[d]), p);
            }
            s[t] = p;
        }
#pragma unroll
        for (int t = 0; t < 5; ++t) s[t] += __shfl_xor(s[t], 1);
#pragma unroll
        for (int t = 0; t < 5; ++t) s[t] += __shfl_xor(s[t], 2);
#pragma unroll
        for (int t = 0; t < 5; ++t)
            s[t] = (jc + t <= j1) ? s[t] * 0.125f : -1e30f;

        float cm = fmaxf(fmaxf(fmaxf(s[0], s[1]), fmaxf(s[2], s[3])), s[4]);
        float nm = fmaxf(mx, cm);
        float corr = __expf(mx - nm);
        l *= corr;
#pragma unroll
        for (int t = 0; t < 16; ++t) acc[t] *= corr;
#pragma unroll
        for (int t = 0; t < 5; ++t) {
            const float e = __expf(s[t] - nm);
            l += e;
            const size_t voff = (size_t)(b * S_ + jj[t]) * HC_ + 1536 + h * HD_ + d0;
            bf16x8 va = *reinterpret_cast<const bf16x8*>(&QKV[voff]);
            bf16x8 vb = *reinterpret_cast<const bf16x8*>(&QKV[voff + 8]);
#pragma unroll
            for (int d = 0; d < 8; ++d) {
                acc[d]     = fmaf(e, bf2f((unsigned short)va[d]), acc[d]);
                acc[d + 8] = fmaf(e, bf2f((unsigned short)vb[d]), acc[d + 8]);
            }
        }
        mx = nm;
    }

    if (valid) {
        const float inv = 1.f / l;
        bf16x8 o0, o1;
#pragma unroll
        for (int t = 0; t < 8; ++t) {
            o0[t] = (short)f2bf(acc[t] * inv);
            o1[t] = (short)f2bf(acc[t + 8] * inv);
        }
        unsigned short* dst = &ctx[(size_t)(b * S_ + i) * H_ + h * HD_ + d0];
        *reinterpret_cast<bf16x8*>(dst) = o0;
        *reinterpret_cast<bf16x8*>(dst + 8) = o1;
    }
}

// ---------- kernel 5: in-place LayerNorm over rows of d_out ----------
__global__ __launch_bounds__(256)
void ln_kernel(float* __restrict__ y, const float* __restrict__ g, const float* __restrict__ bta) {
    int row = blockIdx.x;
    int tid = threadIdx.x;
    float* p = y + (size_t)row * H_;
    float v[3];
    float s = 0.f, s2 = 0.f;
#pragma unroll
    for (int t = 0; t < 3; ++t) {
        v[t] = p[tid + t * 256];
        s += v[t];
        s2 += v[t] * v[t];
    }
#pragma unroll
    for (int o = 32; o; o >>= 1) {
        s  += __shfl_xor(s, o);
        s2 += __shfl_xor(s2, o);
    }
    __shared__ float ss[4], ss2[4];
    if ((tid & 63) == 0) { ss[tid >> 6] = s; ss2[tid >> 6] = s2; }
    __syncthreads();
    s  = ss[0] + ss[1] + ss[2] + ss[3];
    s2 = ss2[0] + ss2[1] + ss2[2] + ss2[3];
    float mu = s * (1.f / H_);
    float var = s2 * (1.f / H_) - mu * mu;
    float rs = rsqrtf(var + 1e-5f);
#pragma unroll
    for (int t = 0; t < 3; ++t) {
        int c = tid + t * 256;
        p[c] = (v[t] - mu) * rs * g[c] + bta[c];
    }
}

// ---------- launch ----------
extern "C" void kernel_launch(void* const* d_in, const int* in_sizes, int n_in,
                              void* d_out, int out_size, void* d_ws, size_t ws_size,
                              hipStream_t stream) {
    const float* feat  = (const float*)d_in[0];
    const float* pos   = (const float*)d_in[1];
    const float* Wq    = (const float*)d_in[2];
    const float* bq    = (const float*)d_in[3];
    const float* Wk    = (const float*)d_in[4];
    const float* bk    = (const float*)d_in[5];
    const float* Wv    = (const float*)d_in[6];
    const float* bv    = (const float*)d_in[7];
    const float* Wo    = (const float*)d_in[8];
    const float* bo    = (const float*)d_in[9];
    const float* ln_g  = (const float*)d_in[10];
    const float* ln_b  = (const float*)d_in[11];
    const int*   level = (const int*)d_in[12];
    float* out = (float*)d_out;

    char* ws = (char*)d_ws;
    unsigned short* xb   = (unsigned short*)ws;                      // [8000][768]
    unsigned short* Wcat = xb + (size_t)M_ * H_;                     // [3072][768] = Wq|Wk|Wv|Wo
    unsigned short* QKVb = Wcat + (size_t)4 * H_ * H_;               // [8000][2304]
    unsigned short* ctxb = QKVb + (size_t)M_ * HC_;                  // [8000][768]

    // 1) fused x-prep + weight cast
    const int nprep = (int)(((size_t)M_ * H_ / 4 + (size_t)4 * H_ * H_ / 4 + 255) / 256);
    prep_all_kernel<<<nprep, 256, 0, stream>>>(feat, pos, level, xb, Wq, Wk, Wv, Wo, Wcat);
    // 2) QKV = x @ [Wq|Wk|Wv]^T + bias   (grid 63x18 = 1134, 512 thr)
    gemm_qkv5<<<63 * 18, 512, 0, stream>>>(xb, Wcat, bq, bk, bv, QKVb);
    // 3) banded attention -> ctx (bf16)
    attn_kernel<<<B_ * NH_ * 16, 256, 0, stream>>>(QKVb, ctxb, level);
    // 4) y = ctx @ Wo^T + bo + features  (grid 63x12 = 756, 256 thr)
    gemm_out4<<<63 * 12, 256, 0, stream>>>(ctxb, Wcat + (size_t)3 * H_ * H_, bo, feat, out);
    // 5) LayerNorm in place on d_out
    ln_kernel<<<M_, 256, 0, stream>>>(out, ln_g, ln_b);
}